// Round 1
// baseline (216.396 us; speedup 1.0000x reference)
//
#include <hip/hip_runtime.h>
#include <stdint.h>

#define B_   16
#define N_   100
#define D_   1024
#define L_   2000
#define M_   1600      // B_*N_
#define MP_  1664      // padded to 13*128
#define NCAT 3072      // concat of Wc|Wa|Wb outputs

typedef __bf16 bf16x8 __attribute__((ext_vector_type(8)));
typedef float  f32x4  __attribute__((ext_vector_type(4)));

// ---------------- prep: f32 -> bf16 conversions ----------------

__global__ void k_cvt_feature(const float* __restrict__ f, __bf16* __restrict__ fb) {
    int i = blockIdx.x * 256 + threadIdx.x;          // one uint4 (8 bf16) per thread
    long base = (long)i * 8;
    if (base >= (long)MP_ * D_) return;
    union { __bf16 h[8]; uint4 u; } pk;
    if (base < (long)M_ * D_) {
        const float4* p = (const float4*)(f + base);
        float4 x = p[0], y = p[1];
        pk.h[0]=(__bf16)x.x; pk.h[1]=(__bf16)x.y; pk.h[2]=(__bf16)x.z; pk.h[3]=(__bf16)x.w;
        pk.h[4]=(__bf16)y.x; pk.h[5]=(__bf16)y.y; pk.h[6]=(__bf16)y.z; pk.h[7]=(__bf16)y.w;
    } else {
        #pragma unroll
        for (int q = 0; q < 8; ++q) pk.h[q] = (__bf16)0.f;
    }
    ((uint4*)fb)[i] = pk.u;
}

__global__ void k_cvt_weights(const float* __restrict__ W0, const float* __restrict__ W1,
                              const float* __restrict__ Wa, const float* __restrict__ Wb,
                              __bf16* __restrict__ wcat) {
    int i = blockIdx.x * 256 + threadIdx.x;          // one uint4 per thread, 3*2^20 elems total
    long base = (long)i * 8;
    long seg = base >> 20;
    long off = base & ((1l << 20) - 1);
    union { __bf16 h[8]; uint4 u; } pk;
    if (seg == 0) {
        const float4* p0 = (const float4*)(W0 + off);
        const float4* p1 = (const float4*)(W1 + off);
        float4 a0 = p0[0], a1 = p0[1], b0 = p1[0], b1 = p1[1];
        pk.h[0]=(__bf16)(a0.x+b0.x); pk.h[1]=(__bf16)(a0.y+b0.y);
        pk.h[2]=(__bf16)(a0.z+b0.z); pk.h[3]=(__bf16)(a0.w+b0.w);
        pk.h[4]=(__bf16)(a1.x+b1.x); pk.h[5]=(__bf16)(a1.y+b1.y);
        pk.h[6]=(__bf16)(a1.z+b1.z); pk.h[7]=(__bf16)(a1.w+b1.w);
    } else {
        const float* src = (seg == 1) ? Wa : Wb;
        const float4* p = (const float4*)(src + off);
        float4 x = p[0], y = p[1];
        pk.h[0]=(__bf16)x.x; pk.h[1]=(__bf16)x.y; pk.h[2]=(__bf16)x.z; pk.h[3]=(__bf16)x.w;
        pk.h[4]=(__bf16)y.x; pk.h[5]=(__bf16)y.y; pk.h[6]=(__bf16)y.z; pk.h[7]=(__bf16)y.w;
    }
    ((uint4*)wcat)[i] = pk.u;
}

__global__ void k_cvt_bias(const float* __restrict__ bias, __bf16* __restrict__ bb) {
    int i = blockIdx.x * 256 + threadIdx.x;          // 2000*1024/8 = 256000 uint4s
    long base = (long)i * 8;
    const float4* p = (const float4*)(bias + base);
    float4 x = p[0], y = p[1];
    union { __bf16 h[8]; uint4 u; } pk;
    pk.h[0]=(__bf16)x.x; pk.h[1]=(__bf16)x.y; pk.h[2]=(__bf16)x.z; pk.h[3]=(__bf16)x.w;
    pk.h[4]=(__bf16)y.x; pk.h[5]=(__bf16)y.y; pk.h[6]=(__bf16)y.z; pk.h[7]=(__bf16)y.w;
    ((uint4*)bb)[i] = pk.u;
}

// ---------------- fused GEMM: [MP_ x 3072] = fb16 @ wcat^T, 3 epilogues ----------------
// C[m, 0:1024]    = f@Wc^T + feature   -> out0
// C[m, 1024:2048] = f@Wa^T + ba        -> aB
// C[m, 2048:3072] = f@Wb^T + bb_vec    -> bB

#define BM 128
#define BN 128
#define BK 32

__global__ void __launch_bounds__(256)
k_gemm(const __bf16* __restrict__ A, const __bf16* __restrict__ Bw,
       const float* __restrict__ feat, const float* __restrict__ ba,
       const float* __restrict__ bbias,
       float* __restrict__ out0, float* __restrict__ aB, float* __restrict__ bB) {
    __shared__ __align__(16) __bf16 As[BM * BK];
    __shared__ __align__(16) __bf16 Bs[BN * BK];
    int t = threadIdx.x;
    int bm = blockIdx.x, bn = blockIdx.y;
    int lane = t & 63, wave = t >> 6;
    int wrow = wave >> 1, wcol = wave & 1;
    int lrow = lane & 15, quad = lane >> 4;

    f32x4 acc[4][4] = {};
    const __bf16* Ag = A  + (long)(bm * BM) * D_;
    const __bf16* Bg = Bw + (long)(bn * BN) * D_;

    for (int k0 = 0; k0 < D_; k0 += BK) {
        #pragma unroll
        for (int it = 0; it < 2; ++it) {
            int idx = it * 256 + t;          // uint4 index in 8KB tile (512 total)
            int row = idx >> 2;              // 4 x 16B per 32-elem row
            int kq  = idx & 3;
            ((uint4*)As)[idx] = *((const uint4*)(Ag + (long)row * D_ + k0) + kq);
            ((uint4*)Bs)[idx] = *((const uint4*)(Bg + (long)row * D_ + k0) + kq);
        }
        __syncthreads();
        bf16x8 af[4], bf[4];
        #pragma unroll
        for (int i = 0; i < 4; ++i) {
            int r  = wrow * 64 + i * 16 + lrow;
            af[i] = *(const bf16x8*)(As + r * BK + quad * 8);
            int rb = wcol * 64 + i * 16 + lrow;
            bf[i] = *(const bf16x8*)(Bs + rb * BK + quad * 8);
        }
        #pragma unroll
        for (int i = 0; i < 4; ++i)
            #pragma unroll
            for (int j = 0; j < 4; ++j)
                acc[i][j] = __builtin_amdgcn_mfma_f32_16x16x32_bf16(af[i], bf[j], acc[i][j], 0, 0, 0);
        __syncthreads();
    }

    int nbase = bn * BN;
    int seg = nbase >> 10;                   // 128 | 1024, so uniform per block
    float* dst = (seg == 0) ? out0 : (seg == 1 ? aB : bB);
    #pragma unroll
    for (int i = 0; i < 4; ++i) {
        int gm0 = bm * BM + wrow * 64 + i * 16 + quad * 4;
        #pragma unroll
        for (int j = 0; j < 4; ++j) {
            int gn  = nbase + wcol * 64 + j * 16 + lrow;
            int col = gn & 1023;
            #pragma unroll
            for (int r = 0; r < 4; ++r) {
                int m = gm0 + r;
                if (m < M_) {
                    float v = acc[i][j][r];
                    if (seg == 0)      v += feat[(long)m * D_ + col];
                    else if (seg == 1) v += ba[col];
                    else               v += bbias[col];
                    dst[(long)m * D_ + col] = v;
                }
            }
        }
    }
}

// ---------------- bias gather-sum: out0[b,i,:] += sum_j biasB[graph[b,i,j]] ----------------

__global__ void __launch_bounds__(256)
k_gather(const int* __restrict__ graph, const __bf16* __restrict__ biasB,
         float* __restrict__ out0) {
    int bi = blockIdx.x;                     // 0..1599
    int t = threadIdx.x;
    __shared__ int idxs[N_];
    if (t < N_) idxs[t] = graph[(long)bi * N_ + t];
    __syncthreads();
    float a0 = 0.f, a1 = 0.f, a2 = 0.f, a3 = 0.f;
    for (int j = 0; j < N_; ++j) {
        int lb = idxs[j];
        union { uint2 u; __bf16 h[4]; } pk;
        pk.u = ((const uint2*)(biasB + (long)lb * D_))[t];
        a0 += (float)pk.h[0]; a1 += (float)pk.h[1];
        a2 += (float)pk.h[2]; a3 += (float)pk.h[3];
    }
    float4* o = (float4*)(out0 + (long)bi * D_) + t;
    float4 cur = *o;
    cur.x += a0; cur.y += a1; cur.z += a2; cur.w += a3;
    *o = cur;
}

// ---------------- alphaRaw[b,i,j] = relu(dot(a[b,i,:], b[b,j,:])) ----------------

#define TK 64
__global__ void __launch_bounds__(256)
k_alpha(const float* __restrict__ aB, const float* __restrict__ bB,
        float* __restrict__ alphaR) {
    int b = blockIdx.x, bi = blockIdx.y, bj = blockIdx.z;
    int tx = threadIdx.x & 15, ty = threadIdx.x >> 4;
    __shared__ __align__(16) float aT[16][TK + 4];
    __shared__ __align__(16) float bT[16][TK + 4];
    int i = bi * 16 + ty;
    int j = bj * 16 + tx;
    int lrow = threadIdx.x >> 4, c4 = threadIdx.x & 15;
    float sum = 0.f;
    for (int k0 = 0; k0 < D_; k0 += TK) {
        int ga = bi * 16 + lrow;
        int gb = bj * 16 + lrow;
        float4 av = (ga < N_) ? *(const float4*)(aB + ((long)(b * N_ + ga)) * D_ + k0 + c4 * 4)
                              : make_float4(0.f, 0.f, 0.f, 0.f);
        float4 bv = (gb < N_) ? *(const float4*)(bB + ((long)(b * N_ + gb)) * D_ + k0 + c4 * 4)
                              : make_float4(0.f, 0.f, 0.f, 0.f);
        *(float4*)&aT[lrow][c4 * 4] = av;
        *(float4*)&bT[lrow][c4 * 4] = bv;
        __syncthreads();
        #pragma unroll
        for (int kk = 0; kk < TK; ++kk) sum += aT[ty][kk] * bT[tx][kk];
        __syncthreads();
    }
    if (i < N_ && j < N_)
        alphaR[((long)b * N_ + i) * N_ + j] = fmaxf(sum, 0.f);
}

// ---------------- z[b,i,k] = sum_j (graph[b,i,j]!=0) * alphaR[b,j,k] ----------------

__global__ void __launch_bounds__(256)
k_z(const int* __restrict__ graph, const float* __restrict__ alphaR,
    float* __restrict__ z) {
    int b = blockIdx.x, bi = blockIdx.y, bk = blockIdx.z;
    int tx = threadIdx.x & 15, ty = threadIdx.x >> 4;
    int i = bi * 16 + ty, k = bk * 16 + tx;
    __shared__ float aTile[N_][16 + 1];
    __shared__ float adjT[16][N_ + 4];
    for (int idx = threadIdx.x; idx < N_ * 16; idx += 256) {
        int j = idx >> 4, kk = idx & 15;
        int gk = bk * 16 + kk;
        aTile[j][kk] = (gk < N_) ? alphaR[((long)b * N_ + j) * N_ + gk] : 0.f;
    }
    for (int idx = threadIdx.x; idx < 16 * N_; idx += 256) {
        int r = idx / N_, j = idx % N_;
        int gi = bi * 16 + r;
        adjT[r][j] = (gi < N_ && graph[((long)b * N_ + gi) * N_ + j] != 0) ? 1.f : 0.f;
    }
    __syncthreads();
    float s = 0.f;
    for (int j = 0; j < N_; ++j) s += adjT[ty][j] * aTile[j][tx];
    if (i < N_ && k < N_) z[((long)b * N_ + i) * N_ + k] = s;
}

// ---------------- softmax over axis=1 (the i index), per (b,k) column ----------------

__global__ void __launch_bounds__(128)
k_softmax(const float* __restrict__ z, float* __restrict__ S) {
    int b = blockIdx.x, k = blockIdx.y;
    int t = threadIdx.x;
    __shared__ float red[128];
    float v = (t < N_) ? z[((long)b * N_ + t) * N_ + k] : -1e30f;
    red[t] = v; __syncthreads();
    for (int s = 64; s > 0; s >>= 1) {
        if (t < s) red[t] = fmaxf(red[t], red[t + s]);
        __syncthreads();
    }
    float mx = red[0]; __syncthreads();
    float e = (t < N_) ? __expf(v - mx) : 0.f;
    red[t] = e; __syncthreads();
    for (int s = 64; s > 0; s >>= 1) {
        if (t < s) red[t] += red[t + s];
        __syncthreads();
    }
    float inv = 1.f / red[0];
    if (t < N_) S[((long)b * N_ + t) * N_ + k] = e * inv;
}

// ---------------- out[b,m,d] = sum_i S[b,m,i] * out0[b,i,d] ----------------

__global__ void __launch_bounds__(256)
k_final(const float* __restrict__ S, const float* __restrict__ out0,
        float* __restrict__ out) {
    int b = blockIdx.x, bm = blockIdx.y, bd = blockIdx.z;   // bm 0..6, bd 0..15
    int tx = threadIdx.x & 15, ty = threadIdx.x >> 4;
    int m = bm * 16 + ty;
    int d0 = bd * 64 + tx * 4;
    __shared__ float sT[16][N_ + 4];
    for (int idx = threadIdx.x; idx < 16 * N_; idx += 256) {
        int r = idx / N_, j = idx % N_;
        int gm = bm * 16 + r;
        sT[r][j] = (gm < N_) ? S[((long)b * N_ + gm) * N_ + j] : 0.f;
    }
    __syncthreads();
    float4 acc = make_float4(0.f, 0.f, 0.f, 0.f);
    for (int i = 0; i < N_; ++i) {
        float w = sT[ty][i];
        float4 o = *(const float4*)(out0 + ((long)b * N_ + i) * D_ + d0);
        acc.x += w * o.x; acc.y += w * o.y; acc.z += w * o.z; acc.w += w * o.w;
    }
    if (m < N_) *(float4*)(out + ((long)b * N_ + m) * D_ + d0) = acc;
}

// ---------------- launch ----------------

extern "C" void kernel_launch(void* const* d_in, const int* in_sizes, int n_in,
                              void* d_out, int out_size, void* d_ws, size_t ws_size,
                              hipStream_t stream) {
    const float* feature = (const float*)d_in[0];
    const int*   graph   = (const int*)d_in[1];
    const float* W0      = (const float*)d_in[2];
    const float* W1      = (const float*)d_in[3];
    const float* bias    = (const float*)d_in[4];
    const float* dp_Wa   = (const float*)d_in[5];
    const float* dp_ba   = (const float*)d_in[6];
    const float* dp_Wb   = (const float*)d_in[7];
    const float* dp_bb   = (const float*)d_in[8];
    float* out = (float*)d_out;

    char* w = (char*)d_ws;
    __bf16* fb16  = (__bf16*)(w);                    // MP_*D_*2      = 3,407,872
    __bf16* wcat  = (__bf16*)(w + 3407872);          // 3072*1024*2   = 6,291,456
    __bf16* biasB = (__bf16*)(w + 9699328);          // 2000*1024*2   = 4,096,000
    float*  out0  = (float*)(w + 13795328);          // 1600*1024*4   = 6,553,600
    float*  aB    = (float*)(w + 20348928);          // 6,553,600
    float*  bB    = (float*)(w + 26902528);          // 6,553,600
    float*  alphaR= (float*)(w + 33456128);          // 640,000
    float*  zB    = (float*)(w + 34096128);          // 640,000
    float*  S     = (float*)(w + 34736128);          // 640,000

    k_cvt_feature<<<832, 256, 0, stream>>>(feature, fb16);
    k_cvt_weights<<<1536, 256, 0, stream>>>(W0, W1, dp_Wa, dp_Wb, wcat);
    k_cvt_bias<<<1000, 256, 0, stream>>>(bias, biasB);
    k_gemm<<<dim3(13, 24), 256, 0, stream>>>(fb16, wcat, feature, dp_ba, dp_bb, out0, aB, bB);
    k_gather<<<1600, 256, 0, stream>>>(graph, biasB, out0);
    k_alpha<<<dim3(B_, 7, 7), 256, 0, stream>>>(aB, bB, alphaR);
    k_z<<<dim3(B_, 7, 7), 256, 0, stream>>>(graph, alphaR, zB);
    k_softmax<<<dim3(B_, N_), 128, 0, stream>>>(zB, S);
    k_final<<<dim3(B_, 7, 16), 256, 0, stream>>>(S, out0, out);
}

// Round 2
// 186.011 us; speedup vs baseline: 1.1633x; 1.1633x over previous
//
#include <hip/hip_runtime.h>
#include <stdint.h>

#define B_   16
#define N_   100
#define D_   1024
#define L_   2000
#define M_   1600      // B_*N_

typedef __bf16 bf16x8 __attribute__((ext_vector_type(8)));
typedef float  f32x4  __attribute__((ext_vector_type(4)));

__device__ __forceinline__ void gl_lds16(const __bf16* g, __bf16* l) {
    __builtin_amdgcn_global_load_lds(
        (const __attribute__((address_space(1))) void*)g,
        (__attribute__((address_space(3))) void*)l, 16, 0, 0);
}

__device__ __forceinline__ int swz(int r) { return (r + (r >> 2)) & 3; }

// ---------------- prep: f32 -> bf16 conversions ----------------

__global__ void k_cvt_feature(const float* __restrict__ f, __bf16* __restrict__ fb) {
    int i = blockIdx.x * 256 + threadIdx.x;          // one uint4 (8 bf16) per thread; 204800 total
    long base = (long)i * 8;
    const float4* p = (const float4*)(f + base);
    float4 x = p[0], y = p[1];
    union { __bf16 h[8]; uint4 u; } pk;
    pk.h[0]=(__bf16)x.x; pk.h[1]=(__bf16)x.y; pk.h[2]=(__bf16)x.z; pk.h[3]=(__bf16)x.w;
    pk.h[4]=(__bf16)y.x; pk.h[5]=(__bf16)y.y; pk.h[6]=(__bf16)y.z; pk.h[7]=(__bf16)y.w;
    ((uint4*)fb)[i] = pk.u;
}

__global__ void k_cvt_weights(const float* __restrict__ W0, const float* __restrict__ W1,
                              const float* __restrict__ Wa, const float* __restrict__ Wb,
                              __bf16* __restrict__ wcat) {
    int i = blockIdx.x * 256 + threadIdx.x;
    long base = (long)i * 8;
    long seg = base >> 20;
    long off = base & ((1l << 20) - 1);
    union { __bf16 h[8]; uint4 u; } pk;
    if (seg == 0) {
        const float4* p0 = (const float4*)(W0 + off);
        const float4* p1 = (const float4*)(W1 + off);
        float4 a0 = p0[0], a1 = p0[1], b0 = p1[0], b1 = p1[1];
        pk.h[0]=(__bf16)(a0.x+b0.x); pk.h[1]=(__bf16)(a0.y+b0.y);
        pk.h[2]=(__bf16)(a0.z+b0.z); pk.h[3]=(__bf16)(a0.w+b0.w);
        pk.h[4]=(__bf16)(a1.x+b1.x); pk.h[5]=(__bf16)(a1.y+b1.y);
        pk.h[6]=(__bf16)(a1.z+b1.z); pk.h[7]=(__bf16)(a1.w+b1.w);
    } else {
        const float* src = (seg == 1) ? Wa : Wb;
        const float4* p = (const float4*)(src + off);
        float4 x = p[0], y = p[1];
        pk.h[0]=(__bf16)x.x; pk.h[1]=(__bf16)x.y; pk.h[2]=(__bf16)x.z; pk.h[3]=(__bf16)x.w;
        pk.h[4]=(__bf16)y.x; pk.h[5]=(__bf16)y.y; pk.h[6]=(__bf16)y.z; pk.h[7]=(__bf16)y.w;
    }
    ((uint4*)wcat)[i] = pk.u;
}

__global__ void k_cvt_bias(const float* __restrict__ bias, __bf16* __restrict__ bb) {
    int i = blockIdx.x * 256 + threadIdx.x;          // 256000 uint4s
    long base = (long)i * 8;
    const float4* p = (const float4*)(bias + base);
    float4 x = p[0], y = p[1];
    union { __bf16 h[8]; uint4 u; } pk;
    pk.h[0]=(__bf16)x.x; pk.h[1]=(__bf16)x.y; pk.h[2]=(__bf16)x.z; pk.h[3]=(__bf16)x.w;
    pk.h[4]=(__bf16)y.x; pk.h[5]=(__bf16)y.y; pk.h[6]=(__bf16)y.z; pk.h[7]=(__bf16)y.w;
    ((uint4*)bb)[i] = pk.u;
}

// ---------------- fused GEMM: [1600 x 3072] = fb16 @ wcat^T, 3 epilogues ----------------

#define BM 64
#define BN 128
#define BK 32

__global__ void __launch_bounds__(256)
k_gemm(const __bf16* __restrict__ A, const __bf16* __restrict__ Bw,
       const float* __restrict__ feat, const float* __restrict__ ba,
       const float* __restrict__ bbias,
       float* __restrict__ out0,
       __bf16* __restrict__ aHi, __bf16* __restrict__ aLo,
       __bf16* __restrict__ bHi, __bf16* __restrict__ bLo) {
    __shared__ __align__(16) __bf16 As[BM * BK];
    __shared__ __align__(16) __bf16 Bs[BN * BK];
    int t = threadIdx.x;
    int bm = blockIdx.x, bn = blockIdx.y;
    int lane = t & 63, wave = t >> 6;
    int wr = wave & 1, wc = wave >> 1;
    int lrow = lane & 15, quad = lane >> 4;

    f32x4 acc[2][4] = {};
    const __bf16* Ag = A  + (long)(bm * BM) * D_;
    const __bf16* Bg = Bw + (long)(bn * BN) * D_;

    for (int k0 = 0; k0 < D_; k0 += BK) {
        // async global->LDS staging, 16B/lane, XOR-swizzled chunk placement
        {
            int p = t, row = p >> 2, kq = (p & 3) ^ swz(row);
            gl_lds16(Ag + (long)row * D_ + k0 + kq * 8, As + p * 8);
        }
        #pragma unroll
        for (int pi = 0; pi < 2; ++pi) {
            int p = pi * 256 + t, row = p >> 2, kq = (p & 3) ^ swz(row);
            gl_lds16(Bg + (long)row * D_ + k0 + kq * 8, Bs + p * 8);
        }
        __syncthreads();
        bf16x8 af[2], bf[4];
        #pragma unroll
        for (int i = 0; i < 2; ++i) {
            int r = wr * 32 + i * 16 + lrow;
            af[i] = *(const bf16x8*)(As + ((r << 2) | (quad ^ swz(r))) * 8);
        }
        #pragma unroll
        for (int j = 0; j < 4; ++j) {
            int rb = wc * 64 + j * 16 + lrow;
            bf[j] = *(const bf16x8*)(Bs + ((rb << 2) | (quad ^ swz(rb))) * 8);
        }
        #pragma unroll
        for (int i = 0; i < 2; ++i)
            #pragma unroll
            for (int j = 0; j < 4; ++j)
                acc[i][j] = __builtin_amdgcn_mfma_f32_16x16x32_bf16(af[i], bf[j], acc[i][j], 0, 0, 0);
        __syncthreads();
    }

    int nbase = bn * BN;
    int seg = nbase >> 10;                   // uniform per block
    #pragma unroll
    for (int i = 0; i < 2; ++i) {
        int gm0 = bm * BM + wr * 32 + i * 16 + quad * 4;
        #pragma unroll
        for (int j = 0; j < 4; ++j) {
            int gn  = nbase + wc * 64 + j * 16 + lrow;
            int col = gn & 1023;
            #pragma unroll
            for (int r = 0; r < 4; ++r) {
                long m = gm0 + r;            // M=1600 exact, no guard
                float v = acc[i][j][r];
                if (seg == 0) {
                    out0[m * D_ + col] = v + feat[m * D_ + col];
                } else if (seg == 1) {
                    float tv = v + ba[col];
                    __bf16 h = (__bf16)tv;
                    aHi[m * D_ + col] = h;
                    aLo[m * D_ + col] = (__bf16)(tv - (float)h);
                } else {
                    float tv = v + bbias[col];
                    __bf16 h = (__bf16)tv;
                    bHi[m * D_ + col] = h;
                    bLo[m * D_ + col] = (__bf16)(tv - (float)h);
                }
            }
        }
    }
}

// ---------------- bias gather-sum: out0[b,i,:] += sum_j biasB[graph[b,i,j]] ----------------

__global__ void __launch_bounds__(256)
k_gather(const int* __restrict__ graph, const __bf16* __restrict__ biasB,
         float* __restrict__ out0) {
    int bi = blockIdx.x;
    int t = threadIdx.x;
    __shared__ int idxs[N_];
    if (t < N_) idxs[t] = graph[(long)bi * N_ + t];
    __syncthreads();
    float a0 = 0.f, a1 = 0.f, a2 = 0.f, a3 = 0.f;
    for (int j = 0; j < N_; ++j) {
        int lb = idxs[j];
        union { uint2 u; __bf16 h[4]; } pk;
        pk.u = ((const uint2*)(biasB + (long)lb * D_))[t];
        a0 += (float)pk.h[0]; a1 += (float)pk.h[1];
        a2 += (float)pk.h[2]; a3 += (float)pk.h[3];
    }
    float4* o = (float4*)(out0 + (long)bi * D_) + t;
    float4 cur = *o;
    cur.x += a0; cur.y += a1; cur.z += a2; cur.w += a3;
    *o = cur;
}

// ---------------- alpha = relu(a . b^T) via MFMA, hi/lo bf16 split (~fp32 accuracy) ----------

__global__ void __launch_bounds__(256)
k_alpha_mfma(const __bf16* __restrict__ aHi, const __bf16* __restrict__ aLo,
             const __bf16* __restrict__ bHi, const __bf16* __restrict__ bLo,
             float* __restrict__ alphaR) {
    int b = blockIdx.x, bi = blockIdx.y, bj = blockIdx.z;
    int lane = threadIdx.x & 63, wave = threadIdx.x >> 6;
    int wr = wave & 1, wc = wave >> 1;
    int lrow = lane & 15, quad = lane >> 4;
    int i0 = bi * 32 + wr * 16, j0 = bj * 32 + wc * 16;
    long arow = (long)(b * N_ + i0 + lrow) * D_;     // may read a few rows past 1600 -> masked later
    long brow = (long)(b * N_ + j0 + lrow) * D_;
    f32x4 acc = {};
    #pragma unroll 4
    for (int k0 = 0; k0 < D_; k0 += 32) {
        long ka = arow + k0 + quad * 8;
        long kb = brow + k0 + quad * 8;
        bf16x8 ah = *(const bf16x8*)(aHi + ka);
        bf16x8 al = *(const bf16x8*)(aLo + ka);
        bf16x8 bh = *(const bf16x8*)(bHi + kb);
        bf16x8 bl = *(const bf16x8*)(bLo + kb);
        acc = __builtin_amdgcn_mfma_f32_16x16x32_bf16(ah, bh, acc, 0, 0, 0);
        acc = __builtin_amdgcn_mfma_f32_16x16x32_bf16(ah, bl, acc, 0, 0, 0);
        acc = __builtin_amdgcn_mfma_f32_16x16x32_bf16(al, bh, acc, 0, 0, 0);
    }
    int j = j0 + lrow;
    #pragma unroll
    for (int r = 0; r < 4; ++r) {
        int i = i0 + quad * 4 + r;
        if (i < N_ && j < N_)
            alphaR[((long)b * N_ + i) * N_ + j] = fmaxf(acc[r], 0.f);
    }
}

// ---------------- z[b,i,k] = sum_j (graph[b,i,j]!=0) * alphaR[b,j,k] ----------------

__global__ void __launch_bounds__(256)
k_z(const int* __restrict__ graph, const float* __restrict__ alphaR,
    float* __restrict__ z) {
    int b = blockIdx.x, bi = blockIdx.y, bk = blockIdx.z;
    int tx = threadIdx.x & 15, ty = threadIdx.x >> 4;
    int i = bi * 16 + ty, k = bk * 16 + tx;
    __shared__ float aTile[N_][16 + 1];
    __shared__ float adjT[16][N_ + 4];
    for (int idx = threadIdx.x; idx < N_ * 16; idx += 256) {
        int j = idx >> 4, kk = idx & 15;
        int gk = bk * 16 + kk;
        aTile[j][kk] = (gk < N_) ? alphaR[((long)b * N_ + j) * N_ + gk] : 0.f;
    }
    for (int idx = threadIdx.x; idx < 16 * N_; idx += 256) {
        int r = idx / N_, j = idx % N_;
        int gi = bi * 16 + r;
        adjT[r][j] = (gi < N_ && graph[((long)b * N_ + gi) * N_ + j] != 0) ? 1.f : 0.f;
    }
    __syncthreads();
    float s = 0.f;
    for (int j = 0; j < N_; ++j) s += adjT[ty][j] * aTile[j][tx];
    if (i < N_ && k < N_) z[((long)b * N_ + i) * N_ + k] = s;
}

// ---------------- softmax over axis=1 per (b,k) column; writes bf16 S [b][112][128] ---------

__global__ void __launch_bounds__(128)
k_softmax(const float* __restrict__ z, __bf16* __restrict__ Sb) {
    int b = blockIdx.x, k = blockIdx.y;
    int t = threadIdx.x;
    __shared__ float red[128];
    float v = (t < N_) ? z[((long)b * N_ + t) * N_ + k] : -1e30f;
    red[t] = v; __syncthreads();
    for (int s = 64; s > 0; s >>= 1) {
        if (t < s) red[t] = fmaxf(red[t], red[t + s]);
        __syncthreads();
    }
    float mx = red[0]; __syncthreads();
    float e = (t < N_) ? __expf(v - mx) : 0.f;
    red[t] = e; __syncthreads();
    for (int s = 64; s > 0; s >>= 1) {
        if (t < s) red[t] += red[t + s];
        __syncthreads();
    }
    float inv = 1.f / red[0];
    if (t < N_) Sb[((long)b * 112 + t) * 128 + k] = (__bf16)(e * inv);
}

// ---------------- transpose out0 [b][i][d] f32 -> oT [b][d][128] bf16 (i padded w/ 0) -------

__global__ void __launch_bounds__(256)
k_transpose(const float* __restrict__ out0, __bf16* __restrict__ oT) {
    int b = blockIdx.x, dt = blockIdx.y, it = blockIdx.z;   // dt<32, it<4
    int t = threadIdx.x;
    __shared__ float lds[32][36];
    int ii = t >> 3, c4 = (t & 7) * 4;
    int gi = it * 32 + ii;
    float4 v = make_float4(0.f, 0.f, 0.f, 0.f);
    if (gi < N_)
        v = *(const float4*)(out0 + ((long)(b * N_ + gi)) * D_ + dt * 32 + c4);
    *(float4*)&lds[ii][c4] = v;
    __syncthreads();
    int dd = t >> 3, ic = (t & 7) * 4;
    union { __bf16 h[4]; uint2 u; } pk;
    #pragma unroll
    for (int q = 0; q < 4; ++q) pk.h[q] = (__bf16)lds[ic + q][dd];
    *(uint2*)(oT + ((long)b * 1024 + dt * 32 + dd) * 128 + it * 32 + ic) = pk.u;
}

// ---------------- out[b,m,d] = sum_i S[b,m,i] * out0[b,i,d] via MFMA ----------------

__global__ void __launch_bounds__(256)
k_final(const __bf16* __restrict__ Sb, const __bf16* __restrict__ oT,
        float* __restrict__ out) {
    int b = blockIdx.x, mt = blockIdx.y, dq = blockIdx.z;   // mt<7, dq<4
    int lane = threadIdx.x & 63, wave = threadIdx.x >> 6;
    int lrow = lane & 15, quad = lane >> 4;
    int d0 = dq * 256 + wave * 64;
    long sbase = ((long)b * 112 + mt * 16 + lrow) * 128;
    long obase = ((long)b * 1024 + d0) * 128;
    f32x4 acc[4] = {};
    #pragma unroll
    for (int ks = 0; ks < 128; ks += 32) {
        bf16x8 afr = *(const bf16x8*)(Sb + sbase + ks + quad * 8);
        #pragma unroll
        for (int j = 0; j < 4; ++j) {
            bf16x8 bfr = *(const bf16x8*)(oT + obase + (long)(j * 16 + lrow) * 128 + ks + quad * 8);
            acc[j] = __builtin_amdgcn_mfma_f32_16x16x32_bf16(afr, bfr, acc[j], 0, 0, 0);
        }
    }
    #pragma unroll
    for (int j = 0; j < 4; ++j) {
        int d = d0 + j * 16 + lrow;
        #pragma unroll
        for (int r = 0; r < 4; ++r) {
            int m = mt * 16 + quad * 4 + r;
            if (m < N_)
                out[((long)b * N_ + m) * D_ + d] = acc[j][r];
        }
    }
}

// ---------------- launch ----------------

extern "C" void kernel_launch(void* const* d_in, const int* in_sizes, int n_in,
                              void* d_out, int out_size, void* d_ws, size_t ws_size,
                              hipStream_t stream) {
    const float* feature = (const float*)d_in[0];
    const int*   graph   = (const int*)d_in[1];
    const float* W0      = (const float*)d_in[2];
    const float* W1      = (const float*)d_in[3];
    const float* bias    = (const float*)d_in[4];
    const float* dp_Wa   = (const float*)d_in[5];
    const float* dp_ba   = (const float*)d_in[6];
    const float* dp_Wb   = (const float*)d_in[7];
    const float* dp_bb   = (const float*)d_in[8];
    float* out = (float*)d_out;

    char* w = (char*)d_ws;
    __bf16* fb16  = (__bf16*)(w);                    // 1600*1024*2   = 3,276,800 (region 3,407,872)
    __bf16* wcat  = (__bf16*)(w + 3407872);          // 3072*1024*2   = 6,291,456
    __bf16* biasB = (__bf16*)(w + 9699328);          // 2000*1024*2   = 4,096,000
    float*  out0  = (float*)(w + 13795328);          // 1600*1024*4   = 6,553,600
    __bf16* aHi   = (__bf16*)(w + 20348928);         // 3,276,800
    __bf16* aLo   = (__bf16*)(w + 23625728);         // 3,276,800
    __bf16* bHi   = (__bf16*)(w + 26902528);         // 3,276,800
    __bf16* bLo   = (__bf16*)(w + 30179328);         // 3,276,800
    float*  alphaR= (float*)(w + 33456128);          // 640,000
    float*  zB    = (float*)(w + 34096128);          // 640,000
    __bf16* Sb    = (__bf16*)(w);                    // reuse fb16 region (dead after gemm): 458,752
    __bf16* oT    = (__bf16*)(w + 3407872);          // reuse wcat region (dead after gemm): 4,194,304

    k_cvt_feature<<<800, 256, 0, stream>>>(feature, fb16);
    k_cvt_weights<<<1536, 256, 0, stream>>>(W0, W1, dp_Wa, dp_Wb, wcat);
    k_cvt_bias<<<1000, 256, 0, stream>>>(bias, biasB);
    k_gemm<<<dim3(25, 24), 256, 0, stream>>>(fb16, wcat, feature, dp_ba, dp_bb,
                                             out0, aHi, aLo, bHi, bLo);
    k_gather<<<1600, 256, 0, stream>>>(graph, biasB, out0);
    k_transpose<<<dim3(16, 32, 4), 256, 0, stream>>>(out0, oT);
    k_alpha_mfma<<<dim3(B_, 4, 4), 256, 0, stream>>>(aHi, aLo, bHi, bLo, alphaR);
    k_z<<<dim3(B_, 7, 7), 256, 0, stream>>>(graph, alphaR, zB);
    k_softmax<<<dim3(B_, N_), 128, 0, stream>>>(zB, Sb);
    k_final<<<dim3(B_, 7, 4), 256, 0, stream>>>(Sb, oT, out);
}